// Round 1
// baseline (1246.093 us; speedup 1.0000x reference)
//
#include <hip/hip_runtime.h>
#include <math.h>

#define G_   32
#define NPG_ 512
#define N_   16384
#define EPG_ 8192
#define E_   262144
#define D_   256
#define H_   8
#define DH_  32
#define FF_  1024

#define FMA4(ac, s, v) { (ac).x += (s)*(v).x; (ac).y += (s)*(v).y; (ac).z += (s)*(v).z; (ac).w += (s)*(v).w; }

// ---------------------------------------------------------------- LayerNorm
// one wave per row (D=256 -> 64 lanes x float4)
__global__ __launch_bounds__(256) void ln_kernel(const float* __restrict__ in,
                                                 const float* __restrict__ gw,
                                                 const float* __restrict__ bw,
                                                 float* __restrict__ out) {
  const int wave = threadIdx.x >> 6, lane = threadIdx.x & 63;
  const int row = (blockIdx.x << 2) + wave;
  const float4 v = reinterpret_cast<const float4*>(in + (size_t)row * D_)[lane];
  float s = v.x + v.y + v.z + v.w;
#pragma unroll
  for (int off = 32; off > 0; off >>= 1) s += __shfl_xor(s, off);
  const float m = s * (1.0f / D_);
  const float dx = v.x - m, dy = v.y - m, dz = v.z - m, dw = v.w - m;
  float s2 = dx * dx + dy * dy + dz * dz + dw * dw;
#pragma unroll
  for (int off = 32; off > 0; off >>= 1) s2 += __shfl_xor(s2, off);
  const float inv = rsqrtf(s2 * (1.0f / D_) + 1e-5f);
  const float4 g4 = reinterpret_cast<const float4*>(gw)[lane];
  const float4 b4 = reinterpret_cast<const float4*>(bw)[lane];
  float4 o;
  o.x = dx * inv * g4.x + b4.x;
  o.y = dy * inv * g4.y + b4.y;
  o.z = dz * inv * g4.z + b4.z;
  o.w = dw * inv * g4.w + b4.w;
  reinterpret_cast<float4*>(out + (size_t)row * D_)[lane] = o;
}

// ---------------------------------------------------------------- GEMM
// C[M,Nc] = act(A[M,K] @ W[K,Nc] + bias) (+ res).  BM=64 BN=128 BK=32.
// 256 threads: 8 row-groups (ty) x 32 col-groups (tx); each thread 8 rows x 4 cols.
template <int ACT, int RES>
__global__ __launch_bounds__(256) void gemm_kernel(const float* __restrict__ A,
                                                   const float* __restrict__ W,
                                                   const float* __restrict__ bias,
                                                   const float* __restrict__ res,
                                                   float* __restrict__ C,
                                                   int K, int Nc) {
  __shared__ float sA[64][36];
  __shared__ float sW[32][132];
  const int t = threadIdx.x;
  const int row0 = blockIdx.x << 6;
  const int col0 = blockIdx.y << 7;
  const int ty = t >> 5;
  const int tx = t & 31;

  float4 acc[8];
#pragma unroll
  for (int i = 0; i < 8; ++i) { acc[i].x = 0.f; acc[i].y = 0.f; acc[i].z = 0.f; acc[i].w = 0.f; }

  for (int k0 = 0; k0 < K; k0 += 32) {
#pragma unroll
    for (int it = 0; it < 2; ++it) {
      const int idx = t + (it << 8);
      const int r = idx >> 3, c4 = (idx & 7) << 2;
      *reinterpret_cast<float4*>(&sA[r][c4]) =
          *reinterpret_cast<const float4*>(&A[(size_t)(row0 + r) * K + k0 + c4]);
    }
#pragma unroll
    for (int it = 0; it < 4; ++it) {
      const int idx = t + (it << 8);
      const int kk = idx >> 5, c4 = (idx & 31) << 2;
      *reinterpret_cast<float4*>(&sW[kk][c4]) =
          *reinterpret_cast<const float4*>(&W[(size_t)(k0 + kk) * Nc + col0 + c4]);
    }
    __syncthreads();
#pragma unroll
    for (int kk = 0; kk < 32; kk += 4) {
      float4 w4[4];
#pragma unroll
      for (int q = 0; q < 4; ++q)
        w4[q] = *reinterpret_cast<const float4*>(&sW[kk + q][tx << 2]);
      float4 a4[8];
#pragma unroll
      for (int i = 0; i < 8; ++i)
        a4[i] = *reinterpret_cast<const float4*>(&sA[(ty << 3) + i][kk]);
#pragma unroll
      for (int i = 0; i < 8; ++i) {
        FMA4(acc[i], a4[i].x, w4[0]);
        FMA4(acc[i], a4[i].y, w4[1]);
        FMA4(acc[i], a4[i].z, w4[2]);
        FMA4(acc[i], a4[i].w, w4[3]);
      }
    }
    __syncthreads();
  }

  const float4 b4 = *reinterpret_cast<const float4*>(&bias[col0 + (tx << 2)]);
#pragma unroll
  for (int i = 0; i < 8; ++i) {
    const int r = row0 + (ty << 3) + i;
    float4 o = acc[i];
    o.x += b4.x; o.y += b4.y; o.z += b4.z; o.w += b4.w;
    if (ACT) {
      o.x = fmaxf(o.x, 0.f); o.y = fmaxf(o.y, 0.f);
      o.z = fmaxf(o.z, 0.f); o.w = fmaxf(o.w, 0.f);
    }
    if (RES) {
      const float4 r4 = *reinterpret_cast<const float4*>(&res[(size_t)r * Nc + col0 + (tx << 2)]);
      o.x += r4.x; o.y += r4.y; o.z += r4.z; o.w += r4.w;
    }
    *reinterpret_cast<float4*>(&C[(size_t)r * Nc + col0 + (tx << 2)]) = o;
  }
}

// ---------------------------------------------------------------- Attention
// One WG per (g, h, 32-row q-tile). Grid = 32*8*16 = 4096, 256 threads.
// Dynamic LDS: scores[32][520] + q[32][36] + kv[512][36] + mask[32][16]u32.
__global__ __launch_bounds__(256) void attn_kernel(
    const float* __restrict__ qb, const float* __restrict__ kb,
    const float* __restrict__ vb, const int* __restrict__ ei,
    const float* __restrict__ ea, const float* __restrict__ wep,
    const float* __restrict__ bep, const float* __restrict__ weg,
    const float* __restrict__ beg, const float* __restrict__ relpos,
    const float* __restrict__ x, float* __restrict__ x1) {
  extern __shared__ float smem[];
  float* s_sc = smem;                       // [32][520]
  float* s_q = smem + 32 * 520;             // [32][36]
  float* s_kv = s_q + 32 * 36;              // [512][36]
  unsigned* s_mask = reinterpret_cast<unsigned*>(s_kv + 512 * 36);  // [32][16]

  const int t = threadIdx.x;
  const int b = blockIdx.x;
  const int qt = b & 15;
  const int h = (b >> 4) & 7;
  const int g = b >> 7;
  const int n0 = (g << 9) + (qt << 5);

  for (int i = t; i < 32 * 520; i += 256) s_sc[i] = 0.0f;
  for (int i = t; i < 512; i += 256) s_mask[i] = 0u;

  {  // q tile [32][32]
    const int r = t >> 3, c4 = (t & 7) << 2;
    *reinterpret_cast<float4*>(&s_q[r * 36 + c4]) =
        *reinterpret_cast<const float4*>(&qb[(size_t)(n0 + r) * D_ + (h << 5) + c4]);
  }
#pragma unroll
  for (int it = 0; it < 16; ++it) {  // K slab [512][32]
    const int idx = t + (it << 8);
    const int r = idx >> 3, c4 = (idx & 7) << 2;
    *reinterpret_cast<float4*>(&s_kv[r * 36 + c4]) =
        *reinterpret_cast<const float4*>(&kb[(size_t)((g << 9) + r) * D_ + (h << 5) + c4]);
  }
  __syncthreads();

  {  // edge-bias scatter (compute gated edge weight on the fly)
    const float wp0 = wep[h], wp1 = wep[H_ + h], bp = bep[h];
    const float wg0 = weg[h], wg1 = weg[H_ + h], bg = beg[h];
    const int ebase = g << 13;
#pragma unroll 2
    for (int it = 0; it < 32; ++it) {
      const int e = ebase + t + (it << 8);
      const int src = ei[e];
      const int ls = src & 511;
      if ((ls >> 5) == qt) {
        const int dst = ei[E_ + e];
        const int ld = dst & 511;
        const float2 a2 = reinterpret_cast<const float2*>(ea)[e];
        const float pre = a2.x * wp0 + a2.y * wp1 + bp;
        const float gat = a2.x * wg0 + a2.y * wg1 + bg;
        const float ew = pre / (1.0f + __expf(-gat));
        atomicAdd(&s_sc[(ls & 31) * 520 + ld], ew);
        if (g == 0) atomicOr(&s_mask[((ls & 31) << 4) + (ld >> 5)], 1u << (ld & 31));
      }
    }
  }
  __syncthreads();

  {  // QK^T: 4 row-groups x 64 col-groups; 8x8 per thread
    const int rg = t >> 6;
    const int cg = t & 63;
    float acc[8][8];
#pragma unroll
    for (int i = 0; i < 8; ++i)
#pragma unroll
      for (int j = 0; j < 8; ++j) acc[i][j] = 0.0f;
#pragma unroll
    for (int kkg = 0; kkg < 8; ++kkg) {
      float4 q4[8];
#pragma unroll
      for (int i = 0; i < 8; ++i)
        q4[i] = *reinterpret_cast<const float4*>(&s_q[((rg << 3) + i) * 36 + (kkg << 2)]);
#pragma unroll
      for (int j = 0; j < 8; ++j) {
        const float4 k4 =
            *reinterpret_cast<const float4*>(&s_kv[((cg << 3) + j) * 36 + (kkg << 2)]);
#pragma unroll
        for (int i = 0; i < 8; ++i)
          acc[i][j] += q4[i].x * k4.x + q4[i].y * k4.y + q4[i].z * k4.z + q4[i].w * k4.w;
      }
    }
    const float scale = 0.17677669529663687f;  // 1/sqrt(32)
    const float rp = relpos[h];
#pragma unroll
    for (int i = 0; i < 8; ++i) {
      const int r = (rg << 3) + i;
#pragma unroll
      for (int j = 0; j < 8; ++j) {
        const int c = (cg << 3) + j;
        float val = s_sc[r * 520 + c] + acc[i][j] * scale;
        if (g == 0 && ((s_mask[(r << 4) + (c >> 5)] >> (c & 31)) & 1u)) val += rp;
        s_sc[r * 520 + c] = val;
      }
    }
  }
  __syncthreads();

#pragma unroll
  for (int it = 0; it < 16; ++it) {  // restage V slab into s_kv
    const int idx = t + (it << 8);
    const int r = idx >> 3, c4 = (idx & 7) << 2;
    *reinterpret_cast<float4*>(&s_kv[r * 36 + c4]) =
        *reinterpret_cast<const float4*>(&vb[(size_t)((g << 9) + r) * D_ + (h << 5) + c4]);
  }
  {  // softmax: 8 threads per row, 64 cols each
    const int r = t >> 3, seg = (t & 7) << 6;
    float* rowp = &s_sc[r * 520 + seg];
    float mx = -1e30f;
#pragma unroll
    for (int c = 0; c < 64; c += 4) {
      const float4 p = *reinterpret_cast<const float4*>(&rowp[c]);
      mx = fmaxf(mx, fmaxf(fmaxf(p.x, p.y), fmaxf(p.z, p.w)));
    }
#pragma unroll
    for (int off = 1; off < 8; off <<= 1) mx = fmaxf(mx, __shfl_xor(mx, off));
    float sum = 0.0f;
#pragma unroll
    for (int c = 0; c < 64; c += 4) {
      float4 p = *reinterpret_cast<float4*>(&rowp[c]);
      p.x = __expf(p.x - mx); p.y = __expf(p.y - mx);
      p.z = __expf(p.z - mx); p.w = __expf(p.w - mx);
      sum += p.x + p.y + p.z + p.w;
      *reinterpret_cast<float4*>(&rowp[c]) = p;
    }
#pragma unroll
    for (int off = 1; off < 8; off <<= 1) sum += __shfl_xor(sum, off);
    const float inv = 1.0f / sum;
#pragma unroll
    for (int c = 0; c < 64; c += 4) {
      float4 p = *reinterpret_cast<float4*>(&rowp[c]);
      p.x *= inv; p.y *= inv; p.z *= inv; p.w *= inv;
      *reinterpret_cast<float4*>(&rowp[c]) = p;
    }
  }
  __syncthreads();

  {  // PV + residual write: thread -> (row r, 4 output dims)
    const int r = t >> 3, c4 = (t & 7) << 2;
    float4 o; o.x = 0.f; o.y = 0.f; o.z = 0.f; o.w = 0.f;
    const float* prow = &s_sc[r * 520];
#pragma unroll 4
    for (int key = 0; key < 512; key += 4) {
      const float4 p = *reinterpret_cast<const float4*>(&prow[key]);
      const float4 v0 = *reinterpret_cast<const float4*>(&s_kv[(key + 0) * 36 + c4]);
      const float4 v1 = *reinterpret_cast<const float4*>(&s_kv[(key + 1) * 36 + c4]);
      const float4 v2 = *reinterpret_cast<const float4*>(&s_kv[(key + 2) * 36 + c4]);
      const float4 v3 = *reinterpret_cast<const float4*>(&s_kv[(key + 3) * 36 + c4]);
      FMA4(o, p.x, v0);
      FMA4(o, p.y, v1);
      FMA4(o, p.z, v2);
      FMA4(o, p.w, v3);
    }
    const size_t oidx = (size_t)(n0 + r) * D_ + (h << 5) + c4;
    const float4 xv = *reinterpret_cast<const float4*>(&x[oidx]);
    o.x += xv.x; o.y += xv.y; o.z += xv.z; o.w += xv.w;
    *reinterpret_cast<float4*>(&x1[oidx]) = o;
  }
}

// ---------------------------------------------------------------- launch
extern "C" void kernel_launch(void* const* d_in, const int* in_sizes, int n_in,
                              void* d_out, int out_size, void* d_ws, size_t ws_size,
                              hipStream_t stream) {
  const float* x    = (const float*)d_in[0];
  const int*   ei   = (const int*)d_in[1];
  const float* ea   = (const float*)d_in[2];
  const float* ln1g = (const float*)d_in[3];
  const float* ln1b = (const float*)d_in[4];
  const float* wq   = (const float*)d_in[5];
  const float* bq   = (const float*)d_in[6];
  const float* wk   = (const float*)d_in[7];
  const float* bk   = (const float*)d_in[8];
  const float* wv   = (const float*)d_in[9];
  const float* bv   = (const float*)d_in[10];
  const float* wep  = (const float*)d_in[11];
  const float* bep  = (const float*)d_in[12];
  const float* weg  = (const float*)d_in[13];
  const float* beg  = (const float*)d_in[14];
  const float* rp   = (const float*)d_in[15];
  const float* w1   = (const float*)d_in[16];
  const float* b1   = (const float*)d_in[17];
  const float* w2   = (const float*)d_in[18];
  const float* b2   = (const float*)d_in[19];
  const float* ln2g = (const float*)d_in[20];
  const float* ln2b = (const float*)d_in[21];
  float* out = (float*)d_out;

  float* ws = (float*)d_ws;
  const size_t SZ = (size_t)N_ * D_;  // 4,194,304 floats
  float* xn = ws;            // dead after QKV
  float* qb = ws + SZ;       // dead after attn
  float* kb = ws + 2 * SZ;   // dead after attn
  float* vb = ws + 3 * SZ;   // dead after attn
  float* x1 = ws + 4 * SZ;
  float* h2 = ws + 5 * SZ;
  float* f1 = ws;            // N*FF floats = 4*SZ, aliases xn/qb/kb/vb (dead then)

  // 1. LN1
  hipLaunchKernelGGL(ln_kernel, dim3(N_ / 4), dim3(256), 0, stream, x, ln1g, ln1b, xn);
  // 2. QKV
  dim3 gq(N_ / 64, D_ / 128);
  gemm_kernel<0, 0><<<gq, 256, 0, stream>>>(xn, wq, bq, nullptr, qb, D_, D_);
  gemm_kernel<0, 0><<<gq, 256, 0, stream>>>(xn, wk, bk, nullptr, kb, D_, D_);
  gemm_kernel<0, 0><<<gq, 256, 0, stream>>>(xn, wv, bv, nullptr, vb, D_, D_);
  // 3. attention (+ residual into x1)
  const int smem_attn = (32 * 520 + 32 * 36 + 512 * 36) * 4 + 32 * 16 * 4;  // 146,944 B
  (void)hipFuncSetAttribute(reinterpret_cast<const void*>(attn_kernel),
                            hipFuncAttributeMaxDynamicSharedMemorySize, smem_attn);
  attn_kernel<<<dim3(G_ * H_ * 16), 256, smem_attn, stream>>>(qb, kb, vb, ei, ea, wep, bep,
                                                              weg, beg, rp, x, x1);
  // 4. LN2
  hipLaunchKernelGGL(ln_kernel, dim3(N_ / 4), dim3(256), 0, stream, x1, ln2g, ln2b, h2);
  // 5. FF1 (relu)
  gemm_kernel<1, 0><<<dim3(N_ / 64, FF_ / 128), 256, 0, stream>>>(h2, w1, b1, nullptr, f1, D_, FF_);
  // 6. FF2 (+bias +x1 residual) -> out
  gemm_kernel<0, 1><<<dim3(N_ / 64, D_ / 128), 256, 0, stream>>>(f1, w2, b2, x1, out, FF_, D_);
}